// Round 16
// baseline (353.560 us; speedup 1.0000x reference)
//
#include <hip/hip_runtime.h>

// ---------------------------------------------------------------------------
// LinearAttention on MI355X (gfx950), round 16.
//  - feature-map MLP FUSED into proj epilogue (proj N-tile 128 = one head):
//    Ct[256x128] bf16 in LDS -> GEMM1(+relu) -> Hs -> GEMM2 -> Qf/Kf direct.
//    Deletes fm kernel + Qp/Kp round-trip. Bit-identical math (same bf16
//    round-trip, same fragment-linear weights, same kk order).
//  - V blocks keep R14 bounce epilogue -> Vp.
//  - everything else identical to round 15 (300.3 us, absmax 2.594e-4).
// ---------------------------------------------------------------------------

typedef __bf16 bf16_t;
typedef __bf16 bf16x8 __attribute__((ext_vector_type(8)));
typedef __bf16 bf16x4 __attribute__((ext_vector_type(4)));
typedef float  f32x4  __attribute__((ext_vector_type(4)));

#define FILLV (1.0f / 2048.0f)

#define VMCNT2() asm volatile("s_waitcnt vmcnt(2)" ::: "memory")
#define VMCNT0() asm volatile("s_waitcnt vmcnt(0)" ::: "memory")
#define LGKM0()  asm volatile("s_waitcnt lgkmcnt(0)" ::: "memory")
#define BAR()    __builtin_amdgcn_s_barrier()
#define SCHED0() __builtin_amdgcn_sched_barrier(0)

// async global->LDS, 16B per lane. LDS dest must be linear: base + lane*16.
__device__ __forceinline__ void gload16(const void* g, void* l) {
  __builtin_amdgcn_global_load_lds(
      (__attribute__((address_space(1))) void*)(g),
      (__attribute__((address_space(3))) void*)(l), 16, 0, 0);
}

__device__ __forceinline__ void stage_half(const bf16_t* __restrict__ g,
                                           int h, unsigned char* ldsT, int t) {
  const bf16_t* gh = g + (long)h * 128 * 2048;
  unsigned char* lh = ldsT + h * 16384;
#pragma unroll
  for (int i = 0; i < 2; ++i) {
    const int c = t + i * 512;           // chunk 0..1023 (16B each)
    const int r = c >> 3;                // row in 128-row unit
    const int cc = ((c & 7) ^ (r & 7)) * 8;   // inverse-swizzled col (elems)
    gload16(gh + (long)r * 2048 + cc, lh + c * 16);
  }
}

__device__ __forceinline__ bf16x8 lds_frag(const unsigned char* base,
                                           int row, int kelem) {
  int byte = row * 128 + kelem * 2;
  byte ^= (row & 7) << 4;
  return *(const bf16x8*)(base + byte);
}

// ---------------------------------------------------------------------------
// proj_fm8: 8-phase 256x128 proj GEMM with fused feature-map epilogue.
// Grid 768 (by = bid%48, bx = bid/48 = head). which = by>>4: 0=Q,1=K,2=V.
// Q/K: epilogue computes Qf/Kf = relu(C@W1+b1)@W2+b2 via LDS. V: bounce->Vp.
// Fill: 1 nt-store @P1 + 1 @P2 per K-tile; slots [0, 25165824).
// ---------------------------------------------------------------------------
__global__ __launch_bounds__(512, 1) void proj_fm8(
    const bf16_t* __restrict__ A, const bf16_t* __restrict__ Wt,
    const float* __restrict__ bq, const float* __restrict__ bk,
    const float* __restrict__ bv,
    const bf16_t* __restrict__ W1f, const bf16_t* __restrict__ W2f,
    const float* __restrict__ b1, const float* __restrict__ b2,
    bf16_t* __restrict__ Vp, bf16_t* __restrict__ Qf, bf16_t* __restrict__ Kf,
    float* __restrict__ attn)
{
  __shared__ __align__(16) unsigned char smem[131072];
  const int t = threadIdx.x;
  const int lane = t & 63;
  const int wid = t >> 6;
  const int wr = wid >> 2, wc = wid & 3;          // 2M x 4N wave grid
  const int bid = blockIdx.x;
  const int by = bid % 48, bx = bid / 48;         // same-by -> same XCD
  const int which = by >> 4;
  const bf16_t* Ab = A + (long)by * 256 * 2048;
  const bf16_t* Bb = Wt + (long)which * 4194304 + (long)bx * 128 * 2048;
  const float* bias = which == 0 ? bq : (which == 1 ? bk : bv);

  const int lr = lane & 15;
  const int l8 = (lane >> 4) * 8;
  const f32x4 fv = {FILLV, FILLV, FILLV, FILLV};

  f32x4 acc[8][2];
#pragma unroll
  for (int i = 0; i < 8; ++i)
#pragma unroll
    for (int j = 0; j < 2; ++j) acc[i][j] = (f32x4){0.f, 0.f, 0.f, 0.f};

  // prologue: stage tile 0 into buffer 0 (A0, A1, B = 6 loads/thread)
  stage_half(Ab, 0, smem, t);
  stage_half(Ab, 1, smem, t);
  stage_half(Bb, 0, smem + 32768, t);

  bf16x8 aF[4][2], bF[2][2];

  for (int kt = 0; kt < 32; ++kt) {
    const int cur = kt & 1;
    unsigned char* curA = smem + cur * 49152;
    unsigned char* curB = curA + 32768;
    unsigned char* nxtA = smem + (cur ^ 1) * 49152;
    unsigned char* nxtB = nxtA + 32768;
    const bool hn = kt < 31;
    const bf16_t* An = Ab + (kt + 1) * 64;
    const bf16_t* Bn = Bb + (kt + 1) * 64;
    const int arow = wr * 128 + lr;
    const int brow = wc * 32 + lr;
    f32x4* fillp = (f32x4*)attn + ((long)kt * 768 + bid) * 1024 + t;

    // ---- phase 0
    if (hn) { stage_half(An, 0, nxtA, t); VMCNT2(); }
    else    { VMCNT0(); }
    BAR();
#pragma unroll
    for (int mi = 0; mi < 4; ++mi)
#pragma unroll
      for (int kk = 0; kk < 2; ++kk)
        aF[mi][kk] = lds_frag(curA, arow + mi * 16, kk * 32 + l8);
#pragma unroll
    for (int kk = 0; kk < 2; ++kk)
      bF[0][kk] = lds_frag(curB, brow, kk * 32 + l8);
    LGKM0(); SCHED0();
    __builtin_amdgcn_s_setprio(1);
#pragma unroll
    for (int mi = 0; mi < 4; ++mi)
#pragma unroll
      for (int kk = 0; kk < 2; ++kk)
        acc[mi][0] = __builtin_amdgcn_mfma_f32_16x16x32_bf16(
            aF[mi][kk], bF[0][kk], acc[mi][0], 0, 0, 0);
    __builtin_amdgcn_s_setprio(0);
    BAR();

    // ---- phase 1
    if (hn) stage_half(An, 1, nxtA, t);
    __builtin_nontemporal_store(fv, fillp);
#pragma unroll
    for (int kk = 0; kk < 2; ++kk)
      bF[1][kk] = lds_frag(curB, brow + 16, kk * 32 + l8);
    BAR(); LGKM0(); SCHED0();
    __builtin_amdgcn_s_setprio(1);
#pragma unroll
    for (int mi = 0; mi < 4; ++mi)
#pragma unroll
      for (int kk = 0; kk < 2; ++kk)
        acc[mi][1] = __builtin_amdgcn_mfma_f32_16x16x32_bf16(
            aF[mi][kk], bF[1][kk], acc[mi][1], 0, 0, 0);
    __builtin_amdgcn_s_setprio(0);
    BAR();

    // ---- phase 2
    if (hn) stage_half(Bn, 0, nxtB, t);
    __builtin_nontemporal_store(fv, fillp + 512);
#pragma unroll
    for (int mi = 0; mi < 4; ++mi)
#pragma unroll
      for (int kk = 0; kk < 2; ++kk)
        aF[mi][kk] = lds_frag(curA, arow + 64 + mi * 16, kk * 32 + l8);
    BAR(); LGKM0(); SCHED0();
    __builtin_amdgcn_s_setprio(1);
#pragma unroll
    for (int mi = 0; mi < 4; ++mi)
#pragma unroll
      for (int kk = 0; kk < 2; ++kk)
        acc[4 + mi][0] = __builtin_amdgcn_mfma_f32_16x16x32_bf16(
            aF[mi][kk], bF[0][kk], acc[4 + mi][0], 0, 0, 0);
    __builtin_amdgcn_s_setprio(0);
    BAR();

    // ---- phase 3
    BAR(); SCHED0();
    __builtin_amdgcn_s_setprio(1);
#pragma unroll
    for (int mi = 0; mi < 4; ++mi)
#pragma unroll
      for (int kk = 0; kk < 2; ++kk)
        acc[4 + mi][1] = __builtin_amdgcn_mfma_f32_16x16x32_bf16(
            aF[mi][kk], bF[1][kk], acc[4 + mi][1], 0, 0, 0);
    __builtin_amdgcn_s_setprio(0);
    BAR();
  }

  const int tokBase = (by & 15) * 256;
  const int col0 = wc * 32;

  if (which == 2) {
    // V epilogue: per-wave LDS bounce -> vectorized Vp stores (R14).
    float* lw = (float*)smem + wid * 2304;
#pragma unroll
    for (int p = 0; p < 2; ++p) {
      LGKM0();
#pragma unroll
      for (int mi = 0; mi < 4; ++mi)
#pragma unroll
        for (int ni = 0; ni < 2; ++ni) {
          const float bvv = bias[bx * 128 + col0 + ni * 16 + lr];
#pragma unroll
          for (int j = 0; j < 4; ++j) {
            const int rl = mi * 16 + (lane >> 4) * 4 + j;
            lw[rl * 36 + ni * 16 + lr] = acc[p * 4 + mi][ni][j] + bvv;
          }
        }
      LGKM0(); SCHED0();
#pragma unroll
      for (int i = 0; i < 8; ++i) {
        const int c = i * 64 + lane;
        const int rl = c >> 3, cc = (c & 7) * 4;
        f32x4 v4 = *(const f32x4*)&lw[rl * 36 + cc];
        const int tok = tokBase + wr * 128 + p * 64 + rl;
        bf16x4 o = {(bf16_t)v4[0], (bf16_t)v4[1],
                    (bf16_t)v4[2], (bf16_t)v4[3]};
        *(bf16x4*)&Vp[(long)tok * 2048 + bx * 128 + col0 + cc] = o;
      }
    }
    return;
  }

  // ---- Q/K: fused feature map ----
  unsigned char* Ct = smem;            // [256 rows][256B] bf16, swizzled
  unsigned char* Hs = smem + 65536;    // [128 rows][512B] bf16, swizzled

  // 1. write C (+proj bias, cvt bf16) into Ct
#pragma unroll
  for (int mi = 0; mi < 8; ++mi)
#pragma unroll
    for (int ni = 0; ni < 2; ++ni) {
      const int col = col0 + ni * 16 + lr;
      const float bvv = bias[bx * 128 + col];
#pragma unroll
      for (int j = 0; j < 4; ++j) {
        const int row = wr * 128 + mi * 16 + (lane >> 4) * 4 + j;
        int byte = (row << 8) + (col << 1);
        byte ^= (row & 7) << 4;
        *(bf16_t*)(Ct + byte) = (bf16_t)(acc[mi][ni][j] + bvv);
      }
    }
  __syncthreads();

  bf16_t* dst = which == 0 ? Qf : Kf;
  const int wr2 = wid >> 2, wc2 = wid & 3;
  const int lk = lane >> 4;

#pragma unroll
  for (int p = 0; p < 2; ++p) {
    // 2. GEMM1 half: H[128][256] = relu(Ct[p*128..][128] @ W1^T + b1)
    f32x4 a1[4][4];
#pragma unroll
    for (int i = 0; i < 4; ++i)
#pragma unroll
      for (int j = 0; j < 4; ++j) a1[i][j] = (f32x4){0.f, 0.f, 0.f, 0.f};
#pragma unroll
    for (int kk = 0; kk < 4; ++kk) {
      bf16x8 af[4], bfr[4];
#pragma unroll
      for (int mi = 0; mi < 4; ++mi) {
        const int row = p * 128 + wr2 * 64 + mi * 16 + lr;
        int byte = (row << 8) + (kk * 64 + lk * 16);
        byte ^= (row & 7) << 4;
        af[mi] = *(const bf16x8*)(Ct + byte);
      }
#pragma unroll
      for (int ni = 0; ni < 4; ++ni)
        bfr[ni] = *(const bf16x8*)&W1f[((((wc2 << 2) + ni) << 2) + kk) * 512
                                       + lane * 8];
#pragma unroll
      for (int mi = 0; mi < 4; ++mi)
#pragma unroll
        for (int ni = 0; ni < 4; ++ni)
          a1[mi][ni] = __builtin_amdgcn_mfma_f32_16x16x32_bf16(
              af[mi], bfr[ni], a1[mi][ni], 0, 0, 0);
    }
    if (p) __syncthreads();   // p=1: ensure p=0's Hs reads are done
#pragma unroll
    for (int ni = 0; ni < 4; ++ni) {
      const int col = wc2 * 64 + ni * 16 + lr;
      const float bvv = b1[col];
#pragma unroll
      for (int mi = 0; mi < 4; ++mi)
#pragma unroll
        for (int j = 0; j < 4; ++j) {
          const int row = wr2 * 64 + mi * 16 + lk * 4 + j;
          float h = fmaxf(a1[mi][ni][j] + bvv, 0.f);
          int byte = (row << 9) + (col << 1);
          byte ^= (row & 7) << 4;
          *(bf16_t*)(Hs + byte) = (bf16_t)h;
        }
    }
    __syncthreads();

    // 3. GEMM2 half: Out[128][128] = Hs @ W2^T + b2 -> Qf/Kf
    f32x4 a2[4][2];
#pragma unroll
    for (int i = 0; i < 4; ++i)
#pragma unroll
      for (int j = 0; j < 2; ++j) a2[i][j] = (f32x4){0.f, 0.f, 0.f, 0.f};
#pragma unroll
    for (int kk = 0; kk < 8; ++kk) {
      bf16x8 af[4], bfr[2];
#pragma unroll
      for (int mi = 0; mi < 4; ++mi) {
        const int row = wr2 * 64 + mi * 16 + lr;
        int byte = (row << 9) + (kk * 64 + lk * 16);
        byte ^= (row & 7) << 4;
        af[mi] = *(const bf16x8*)(Hs + byte);
      }
#pragma unroll
      for (int ni = 0; ni < 2; ++ni)
        bfr[ni] = *(const bf16x8*)&W2f[((((wc2 << 1) + ni) << 3) + kk) * 512
                                       + lane * 8];
#pragma unroll
      for (int mi = 0; mi < 4; ++mi)
#pragma unroll
        for (int ni = 0; ni < 2; ++ni)
          a2[mi][ni] = __builtin_amdgcn_mfma_f32_16x16x32_bf16(
              af[mi], bfr[ni], a2[mi][ni], 0, 0, 0);
    }
#pragma unroll
    for (int ni = 0; ni < 2; ++ni) {
      const int col = wc2 * 32 + ni * 16 + lr;
      const float bvv = b2[col];
#pragma unroll
      for (int mi = 0; mi < 4; ++mi)
#pragma unroll
        for (int j = 0; j < 4; ++j) {
          const int rl = wr2 * 64 + mi * 16 + lk * 4 + j;
          const int tok = tokBase + p * 128 + rl;
          dst[(long)tok * 2048 + bx * 128 + col] =
              (bf16_t)(a2[mi][ni][j] + bvv);
        }
    }
  }
}

// ---------------------------------------------------------------------------
// 8-phase 256x128 output GEMM (single weight, f32 out, fill).
// ---------------------------------------------------------------------------
__global__ __launch_bounds__(512, 2) void gemm8out(
    const bf16_t* __restrict__ A, const bf16_t* __restrict__ Wt,
    const float* __restrict__ b0, float* __restrict__ C,
    float* __restrict__ attn, long fillBase)
{
  __shared__ __align__(16) unsigned char smem[98304];
  const int t = threadIdx.x;
  const int lane = t & 63;
  const int wid = t >> 6;
  const int wr = wid >> 2, wc = wid & 3;
  const int bid = blockIdx.x;
  const int nby = gridDim.x >> 4;
  const int by = bid % nby, bx = bid / nby;
  const bf16_t* Ab = A + (long)by * 256 * 2048;
  const bf16_t* Bb = Wt + (long)bx * 128 * 2048;

  const int lr = lane & 15;
  const int l8 = (lane >> 4) * 8;
  const f32x4 fv = {FILLV, FILLV, FILLV, FILLV};
  const int nblk = gridDim.x;

  f32x4 acc[8][2];
#pragma unroll
  for (int i = 0; i < 8; ++i)
#pragma unroll
    for (int j = 0; j < 2; ++j) acc[i][j] = (f32x4){0.f, 0.f, 0.f, 0.f};

  stage_half(Ab, 0, smem, t);
  stage_half(Ab, 1, smem, t);
  stage_half(Bb, 0, smem + 32768, t);

  bf16x8 aF[4][2], bF[2][2];

  for (int kt = 0; kt < 32; ++kt) {
    const int cur = kt & 1;
    unsigned char* curA = smem + cur * 49152;
    unsigned char* curB = curA + 32768;
    unsigned char* nxtA = smem + (cur ^ 1) * 49152;
    unsigned char* nxtB = nxtA + 32768;
    const bool hn = kt < 31;
    const bf16_t* An = Ab + (kt + 1) * 64;
    const bf16_t* Bn = Bb + (kt + 1) * 64;
    const int arow = wr * 128 + lr;
    const int brow = wc * 32 + lr;
    f32x4* fillp = (f32x4*)attn + fillBase + ((long)kt * nblk + bid) * 1024 + t;

    if (hn) { stage_half(An, 0, nxtA, t); VMCNT2(); }
    else    { VMCNT0(); }
    BAR();
#pragma unroll
    for (int mi = 0; mi < 4; ++mi)
#pragma unroll
      for (int kk = 0; kk < 2; ++kk)
        aF[mi][kk] = lds_frag(curA, arow + mi * 16, kk * 32 + l8);
#pragma unroll
    for (int kk = 0; kk < 2; ++kk)
      bF[0][kk] = lds_frag(curB, brow, kk * 32 + l8);
    LGKM0(); SCHED0();
    __builtin_amdgcn_s_setprio(1);
#pragma unroll
    for (int mi = 0; mi < 4; ++mi)
#pragma unroll
      for (int kk = 0; kk < 2; ++kk)
        acc[mi][0] = __builtin_amdgcn_mfma_f32_16x16x32_bf16(
            aF[mi][kk], bF[0][kk], acc[mi][0], 0, 0, 0);
    __builtin_amdgcn_s_setprio(0);
    BAR();

    if (hn) stage_half(An, 1, nxtA, t);
    __builtin_nontemporal_store(fv, fillp);
#pragma unroll
    for (int kk = 0; kk < 2; ++kk)
      bF[1][kk] = lds_frag(curB, brow + 16, kk * 32 + l8);
    BAR(); LGKM0(); SCHED0();
    __builtin_amdgcn_s_setprio(1);
#pragma unroll
    for (int mi = 0; mi < 4; ++mi)
#pragma unroll
      for (int kk = 0; kk < 2; ++kk)
        acc[mi][1] = __builtin_amdgcn_mfma_f32_16x16x32_bf16(
            aF[mi][kk], bF[1][kk], acc[mi][1], 0, 0, 0);
    __builtin_amdgcn_s_setprio(0);
    BAR();

    if (hn) stage_half(Bn, 0, nxtB, t);
    __builtin_nontemporal_store(fv, fillp + 512);
#pragma unroll
    for (int mi = 0; mi < 4; ++mi)
#pragma unroll
      for (int kk = 0; kk < 2; ++kk)
        aF[mi][kk] = lds_frag(curA, arow + 64 + mi * 16, kk * 32 + l8);
    BAR(); LGKM0(); SCHED0();
    __builtin_amdgcn_s_setprio(1);
#pragma unroll
    for (int mi = 0; mi < 4; ++mi)
#pragma unroll
      for (int kk = 0; kk < 2; ++kk)
        acc[4 + mi][0] = __builtin_amdgcn_mfma_f32_16x16x32_bf16(
            aF[mi][kk], bF[0][kk], acc[4 + mi][0], 0, 0, 0);
    __builtin_amdgcn_s_setprio(0);
    BAR();

    BAR(); SCHED0();
    __builtin_amdgcn_s_setprio(1);
#pragma unroll
    for (int mi = 0; mi < 4; ++mi)
#pragma unroll
      for (int kk = 0; kk < 2; ++kk)
        acc[4 + mi][1] = __builtin_amdgcn_mfma_f32_16x16x32_bf16(
            aF[mi][kk], bF[1][kk], acc[4 + mi][1], 0, 0, 0);
    __builtin_amdgcn_s_setprio(0);
    BAR();
  }

  const int row0g = by * 256 + wr * 128;
  const int col0g = bx * 128 + wc * 32;
  float* lw = (float*)smem + wid * 2304;
#pragma unroll
  for (int p = 0; p < 2; ++p) {
    LGKM0();
#pragma unroll
    for (int mi = 0; mi < 4; ++mi)
#pragma unroll
      for (int ni = 0; ni < 2; ++ni) {
        const float bvv = b0[col0g + ni * 16 + lr];
#pragma unroll
        for (int j = 0; j < 4; ++j) {
          const int rl = mi * 16 + (lane >> 4) * 4 + j;
          lw[rl * 36 + ni * 16 + lr] = acc[p * 4 + mi][ni][j] + bvv;
        }
      }
    LGKM0(); SCHED0();
#pragma unroll
    for (int i = 0; i < 8; ++i) {
      const int c = i * 64 + lane;
      const int rl = c >> 3, cc = (c & 7) * 4;
      f32x4 v4 = *(const f32x4*)&lw[rl * 36 + cc];
      *(f32x4*)&C[(long)(row0g + p * 64 + rl) * 2048 + col0g + cc] = v4;
    }
  }
}

// ---------------------------------------------------------------------------
// m97-style bf16 GEMM (ctx only): C = A @ Bt^T, batched over grid.z.
// ---------------------------------------------------------------------------
__global__ __launch_bounds__(256) void gemm_bt(
    const bf16_t* __restrict__ A, const bf16_t* __restrict__ Bt,
    bf16_t* __restrict__ C, int K, int lda, int ldb, int ldc,
    long aBatchB, long aBatchH, long bBatchB, long bBatchH,
    long cBatchB, long cBatchH, int HperB)
{
  __shared__ bf16_t As[128 * 64];
  __shared__ bf16_t Bs[128 * 64];

  const int z  = blockIdx.z;
  const int zb = z / HperB, zh = z % HperB;
  const bf16_t* Ab = A  + (long)zb * aBatchB + (long)zh * aBatchH
                        + (long)blockIdx.y * 128 * lda;
  const bf16_t* Bb = Bt + (long)zb * bBatchB + (long)zh * bBatchH
                        + (long)blockIdx.x * 128 * ldb;

  const int t = threadIdx.x;
  const int lane = t & 63, w = t >> 6;
  const int wm = (w >> 1) * 64, wn = (w & 1) * 64;

  f32x4 acc[4][4];
#pragma unroll
  for (int i = 0; i < 4; ++i)
#pragma unroll
    for (int j = 0; j < 4; ++j) acc[i][j] = (f32x4){0.f, 0.f, 0.f, 0.f};

  for (int k0 = 0; k0 < K; k0 += 64) {
#pragma unroll
    for (int i = 0; i < 4; ++i) {
      int c = i * 256 + t;
      int row = c >> 3, col = (c & 7) * 8;
      gload16(Ab + (long)row * lda + k0 + col, &As[c * 8]);
      gload16(Bb + (long)row * ldb + k0 + col, &Bs[c * 8]);
    }
    __syncthreads();
#pragma unroll
    for (int kk = 0; kk < 2; ++kk) {
      bf16x8 af[4], bfr[4];
#pragma unroll
      for (int mi = 0; mi < 4; ++mi)
        af[mi] = *(const bf16x8*)&As[(wm + mi * 16 + (lane & 15)) * 64
                                     + kk * 32 + (lane >> 4) * 8];
#pragma unroll
      for (int ni = 0; ni < 4; ++ni)
        bfr[ni] = *(const bf16x8*)&Bs[(wn + ni * 16 + (lane & 15)) * 64
                                      + kk * 32 + (lane >> 4) * 8];
#pragma unroll
      for (int mi = 0; mi < 4; ++mi)
#pragma unroll
        for (int ni = 0; ni < 4; ++ni)
          acc[mi][ni] = __builtin_amdgcn_mfma_f32_16x16x32_bf16(
              af[mi], bfr[ni], acc[mi][ni], 0, 0, 0);
    }
    __syncthreads();
  }

  const long cb = (long)zb * cBatchB + (long)zh * cBatchH;
  const int row0 = blockIdx.y * 128 + wm;
  const int col0 = blockIdx.x * 128 + wn;
#pragma unroll
  for (int mi = 0; mi < 4; ++mi) {
#pragma unroll
    for (int ni = 0; ni < 4; ++ni) {
      const int col = col0 + ni * 16 + (lane & 15);
#pragma unroll
      for (int j = 0; j < 4; ++j) {
        const int row = row0 + mi * 16 + (lane >> 4) * 4 + j;
        C[cb + (long)row * ldc + col] = (bf16_t)acc[mi][ni][j];
      }
    }
  }
}

// ---------------------------------------------------------------------------
// prep v3 (R15): cvt + 64x64 big-W transposes + fragment-linear fm weights.
// ---------------------------------------------------------------------------
__global__ __launch_bounds__(256) void prep(
    const float* __restrict__ q, const float* __restrict__ k,
    const float* __restrict__ v,
    const float* __restrict__ Wq, const float* __restrict__ Wk,
    const float* __restrict__ Wv, const float* __restrict__ Wo,
    const float* __restrict__ Wf1, const float* __restrict__ Wf2,
    bf16_t* __restrict__ qkv_bf, bf16_t* __restrict__ Wqkv_t,
    bf16_t* __restrict__ Wf1_f, bf16_t* __restrict__ Wf2_f)
{
  const int t = threadIdx.x;
  const int bid = blockIdx.x;
  __shared__ float ts[64 * 65];

  if (bid < 12288) {
    const float* in = bid < 4096 ? q : (bid < 8192 ? k : v);
    bf16_t* o = qkv_bf + (long)(bid >> 12) * 8388608L;
    const long base = (long)(bid & 4095) * 2048 + t * 8;
    float4 x0 = *(const float4*)&in[base];
    float4 x1 = *(const float4*)&in[base + 4];
    bf16x8 r = {(bf16_t)x0.x, (bf16_t)x0.y, (bf16_t)x0.z, (bf16_t)x0.w,
                (bf16_t)x1.x, (bf16_t)x1.y, (bf16_t)x1.z, (bf16_t)x1.w};
    *(bf16x8*)&o[base] = r;
    return;
  }

  if (bid >= 16384) {
    const bool isW2 = (bid == 16385);
    const float* Wsrc = isW2 ? Wf2 : Wf1;
    bf16_t* dst = isW2 ? Wf2_f : Wf1_f;
    const int Nd2 = isW2 ? 128 : 256;
#pragma unroll
    for (int i = 0; i < 16; ++i) {
      const int idx = t * 16 + i;
      const int ln = idx & 63;
      int kk, col;
      if (!isW2) {
        kk = (idx >> 6) & 3;
        const int ni = (idx >> 8) & 3, ww = idx >> 10;
        col = ww * 64 + ni * 16 + (ln & 15);
      } else {
        kk = (idx >> 6) & 7;
        const int ni = (idx >> 9) & 1, ww = idx >> 10;
        col = ww * 32 + ni * 16 + (ln & 15);
      }
      const int krow = kk * 32 + (ln >> 4) * 8;
      bf16x8 vv;
#pragma unroll
      for (int e = 0; e < 8; ++e)
        vv[e] = (bf16_t)Wsrc[(long)(krow + e) * Nd2 + col];
      *(bf16x8*)&dst[(long)idx * 8] = vv;
    }
    return;
  }

  const int tile = bid - 12288;
  const int wsel = tile >> 10, r = tile & 1023;
  const float* W = wsel == 0 ? Wq : wsel == 1 ? Wk : wsel == 2 ? Wv : Wo;
  bf16_t* outp = Wqkv_t + (long)wsel * 4194304L;
  const int k0 = (r >> 5) * 64, n0 = (r & 31) * 64;

#pragma unroll
  for (int i = 0; i < 4; ++i) {
    const int idx = i * 256 + t;
    const int rr = idx >> 4, cc = (idx & 15) * 4;
    float4 x = *(const float4*)&W[(long)(k0 + rr) * 2048 + n0 + cc];
    float* p = &ts[rr * 65 + cc];
    p[0] = x.x; p[1] = x.y; p[2] = x.z; p[3] = x.w;
  }
  __syncthreads();

#pragma unroll
  for (int i = 0; i < 2; ++i) {
    const int idx = i * 256 + t;
    const int n = idx >> 3, kc = (idx & 7) * 8;
    bf16x8 vv;
#pragma unroll
    for (int qq = 0; qq < 8; ++qq) vv[qq] = (bf16_t)ts[(kc + qq) * 65 + n];
    *(bf16x8*)&outp[(long)(n0 + n) * 2048 + k0 + kc] = vv;
  }
}

// ---------------------------------------------------------------------------
// Partial KV^T + per-chunk K-sums. Split 8: grid (8, 32), 256 s-rows/block.
// ---------------------------------------------------------------------------
__global__ __launch_bounds__(256) void kv_partial(
    const bf16_t* __restrict__ Kf, const bf16_t* __restrict__ Vp,
    float* __restrict__ part, float* __restrict__ part_denom) {
  const int z = blockIdx.y, b = z >> 4, h = z & 15;
  const int s0 = blockIdx.x * 256;
  const int t = threadIdx.x;
  __shared__ bf16_t Ks[32 * 128];
  __shared__ bf16_t Vs[32 * 128];
  __shared__ float red[4];
  const bf16_t* Kb = Kf + (long)b * 4194304 + h * 128;
  const bf16_t* Vb = Vp + (long)b * 4194304 + h * 128;
  float acc[8][8];
#pragma unroll
  for (int i = 0; i < 8; ++i)
#pragma unroll
    for (int j = 0; j < 8; ++j) acc[i][j] = 0.f;
  float ksum = 0.f;
  const int d0 = (t & 15) * 8, e0 = (t >> 4) * 8;
  for (int sc = 0; sc < 256; sc += 32) {
#pragma unroll
    for (int i = 0; i < 2; ++i) {
      int idx = (i * 256 + t) * 8;
      int r = idx >> 7, c = idx & 127;
      long g = (long)(s0 + sc + r) * 2048 + c;
      *(bf16x8*)&Ks[r * 128 + c] = *(const bf16x8*)&Kb[g];
      *(bf16x8*)&Vs[r * 128 + c] = *(const bf16x8*)&Vb[g];
    }
    __syncthreads();
    {
      bf16x8 a0 = *(const bf16x8*)&Ks[t * 16];
      bf16x8 a1 = *(const bf16x8*)&Ks[t * 16 + 8];
#pragma unroll
      for (int j = 0; j < 8; ++j) ksum += (float)a0[j] + (float)a1[j];
    }
    for (int s = 0; s < 32; ++s) {
      bf16x8 kv = *(const bf16x8*)&Ks[s * 128 + d0];
      bf16x8 vv = *(const bf16x8*)&Vs[s * 128 + e0];
      float kf[8], vf[8];
#pragma unroll
      for (int i = 0; i < 8; ++i) { kf[i] = (float)kv[i]; vf[i] = (float)vv[i]; }
#pragma unroll
      for (int i = 0; i < 8; ++i)
#pragma unroll
        for (int j = 0; j < 8; ++j) acc[i][j] += vf[i] * kf[j];
    }
    __syncthreads();
  }

#pragma unroll
  for (int off = 32; off; off >>= 1) ksum += __shfl_down(ksum, off, 64);
  if ((t & 63) == 0) red[t >> 6] = ksum;
  __syncthreads();
  if (t == 0)
    part_denom[blockIdx.x * 32 + z] = red[0] + red[1] + red[2] + red[3];

  float* pb = part + ((long)blockIdx.x * 32 + z) * 16384;
#pragma unroll
  for (int i = 0; i < 8; ++i)
#pragma unroll
    for (int j = 0; j < 8; ++j)
      pb[(e0 + i) * 128 + (d0 + j)] = acc[i][j];
}

// ---------------------------------------------------------------------------
// kv_reduce: 512 blocks; z = bid>>4, slice = bid&15; one float4/thread.
// ---------------------------------------------------------------------------
__global__ __launch_bounds__(256) void kv_reduce(
    const float* __restrict__ part, const float* __restrict__ part_denom,
    bf16_t* __restrict__ KVT) {
  const int z = blockIdx.x >> 4, slice = blockIdx.x & 15;
  const int t = threadIdx.x;
  float dsum = 0.f;
#pragma unroll
  for (int c = 0; c < 8; ++c) dsum += part_denom[c * 32 + z];
  const float inv = 1.0f / (dsum + 1e-8f);
  const long i0 = slice * 1024 + t * 4;
  f32x4 s = {0.f, 0.f, 0.f, 0.f};
#pragma unroll
  for (int c = 0; c < 8; ++c) {
    f32x4 v = *(const f32x4*)&part[((long)c * 32 + z) * 16384 + i0];
    s.x += v.x; s.y += v.y; s.z += v.z; s.w += v.w;
  }
  bf16x4 o = {(bf16_t)(s.x * inv), (bf16_t)(s.y * inv),
              (bf16_t)(s.z * inv), (bf16_t)(s.w * inv)};
  *(bf16x4*)&KVT[(long)z * 16384 + i0] = o;
}

// ---------------------------------------------------------------------------
extern "C" void kernel_launch(void* const* d_in, const int* in_sizes, int n_in,
                              void* d_out, int out_size, void* d_ws, size_t ws_size,
                              hipStream_t stream) {
  (void)in_sizes; (void)n_in; (void)out_size; (void)ws_size;
  const float* q   = (const float*)d_in[0];
  const float* k   = (const float*)d_in[1];
  const float* v   = (const float*)d_in[2];
  const float* Wq  = (const float*)d_in[3];
  const float* bq  = (const float*)d_in[4];
  const float* Wk  = (const float*)d_in[5];
  const float* bk  = (const float*)d_in[6];
  const float* Wv  = (const float*)d_in[7];
  const float* bv  = (const float*)d_in[8];
  const float* Wo  = (const float*)d_in[9];
  const float* bo  = (const float*)d_in[10];
  const float* Wf1 = (const float*)d_in[11];
  const float* bf1 = (const float*)d_in[12];
  const float* Wf2 = (const float*)d_in[13];
  const float* bf2 = (const float*)d_in[14];

  bf16_t* P      = (bf16_t*)d_ws;
  bf16_t* qkv_bf = P;                  // [3][4096][2048]
  bf16_t* Wqkv_t = P + 25165824L;      // [4][2048][2048]
  bf16_t* Wo_t   = P + 37748736L;
  bf16_t* Vp     = P + 58785792L;      // [4096][2048]; later reused as context
  bf16_t* Qf     = P + 83951616L;      // [4096][2048]
  bf16_t* Kf     = P + 92340224L;      // [4096][2048]
  bf16_t* KVT    = P + 100728832L;     // [32][128][128]
  bf16_t* Wf1_f  = P + 101253120L;     // [4096][8] fragment-linear
  bf16_t* Wf2_f  = P + 101285888L;     // [4096][8]
  float*  part   = (float*)d_ws;       // [8][32][128][128] f32 over dead qkv_bf
  float*  part_denom = (float*)d_ws + 4194304L;   // [8][32]

  float* out0 = (float*)d_out;                 // [2,2048,2048]
  float* attn = (float*)d_out + 8388608L;      // [2,16,2048,2048]

  dim3 blk(256);

  // 1. prep: cvt q/k/v + weight transposes + fragment-linear fm weights
  prep<<<16386, blk, 0, stream>>>(q, k, v, Wq, Wk, Wv, Wo, Wf1, Wf2,
                                  qkv_bf, Wqkv_t, Wf1_f, Wf2_f);

  // 2. 8-phase fused QKV projection + feature map (+ fill [0, 25165824))
  proj_fm8<<<768, 512, 0, stream>>>(
      qkv_bf, Wqkv_t, bq, bk, bv, Wf1_f, Wf2_f, bf1, bf2,
      Vp, Qf, Kf, attn);

  // 3. KV^T partials + K-sums (split 8)
  kv_partial<<<dim3(8, 32), blk, 0, stream>>>(Kf, Vp, part, part_denom);

  // 4. reduce partials (+denom)
  kv_reduce<<<512, blk, 0, stream>>>(part, part_denom, KVT);

  // 5. context = Qf @ KVT^T batched over 32 (b,h); overwrite Vp region
  gemm_bt<<<dim3(1, 16, 32), blk, 0, stream>>>(
      Qf, KVT, Vp, 128, 2048, 128, 2048,
      4194304L, 128L, 262144L, 16384L, 4194304L, 128L, 16);

  // 6. output = context @ Wo + bo (+ fill [25165824, 33554432))
  gemm8out<<<256, 512, 0, stream>>>(Vp, Wo_t, bo, out0, attn, 25165824L);
}

// Round 18
// 299.510 us; speedup vs baseline: 1.1805x; 1.1805x over previous
//
#include <hip/hip_runtime.h>

// ---------------------------------------------------------------------------
// LinearAttention on MI355X (gfx950), round 18 = exact revert to round 15
// (300.3 us, absmax 2.594e-4), with R17's compile slip fixed (output GEMM
// is gemm8<true,false>, no phantom gemm8out symbol).
// ---------------------------------------------------------------------------

typedef __bf16 bf16_t;
typedef __bf16 bf16x8 __attribute__((ext_vector_type(8)));
typedef __bf16 bf16x4 __attribute__((ext_vector_type(4)));
typedef float  f32x4  __attribute__((ext_vector_type(4)));

#define FILLV (1.0f / 2048.0f)

#define VMCNT2() asm volatile("s_waitcnt vmcnt(2)" ::: "memory")
#define VMCNT0() asm volatile("s_waitcnt vmcnt(0)" ::: "memory")
#define LGKM0()  asm volatile("s_waitcnt lgkmcnt(0)" ::: "memory")
#define BAR()    __builtin_amdgcn_s_barrier()
#define SCHED0() __builtin_amdgcn_sched_barrier(0)

// async global->LDS, 16B per lane. LDS dest must be linear: base + lane*16.
__device__ __forceinline__ void gload16(const void* g, void* l) {
  __builtin_amdgcn_global_load_lds(
      (__attribute__((address_space(1))) void*)(g),
      (__attribute__((address_space(3))) void*)(l), 16, 0, 0);
}

// ---------------------------------------------------------------------------
// Unified 8-phase 256x128 GEMM: C[M,2048] = A[M,2048] @ Wt[*][2048]^T + bias.
// 512 threads = 8 waves (2M x 4N), per-wave output 128x32.
// LDS 96 KiB dbuf; LDS-bounce vectorized C epilogue (R14).
// Block remap: by = p % nby -> same-A-panel blocks share XCD (R13).
// ---------------------------------------------------------------------------
__device__ __forceinline__ void stage_half(const bf16_t* __restrict__ g,
                                           int h, unsigned char* ldsT, int t) {
  const bf16_t* gh = g + (long)h * 128 * 2048;
  unsigned char* lh = ldsT + h * 16384;
#pragma unroll
  for (int i = 0; i < 2; ++i) {
    const int c = t + i * 512;           // chunk 0..1023 (16B each)
    const int r = c >> 3;                // row in 128-row unit
    const int cc = ((c & 7) ^ (r & 7)) * 8;   // inverse-swizzled col (elems)
    gload16(gh + (long)r * 2048 + cc, lh + c * 16);
  }
}

__device__ __forceinline__ bf16x8 lds_frag(const unsigned char* base,
                                           int row, int kelem) {
  int byte = row * 128 + kelem * 2;
  byte ^= (row & 7) << 4;
  return *(const bf16x8*)(base + byte);
}

template<bool OUTF32, bool TRIPLE>
__global__ __launch_bounds__(512, 2) void gemm8(
    const bf16_t* __restrict__ A, const bf16_t* __restrict__ Wt,
    const float* __restrict__ b0, const float* __restrict__ b1,
    const float* __restrict__ b2, void* __restrict__ C,
    float* __restrict__ attn, long fillBase)
{
  __shared__ __align__(16) unsigned char smem[98304];
  const int t = threadIdx.x;
  const int lane = t & 63;
  const int wid = t >> 6;
  const int wr = wid >> 2, wc = wid & 3;          // 2M x 4N wave grid
  const int bid = blockIdx.x;
  const int nby = gridDim.x >> 4;                 // M/256 M-tiles
  const int by = bid % nby, bx = bid / nby;       // same-by -> same XCD
  const int which = TRIPLE ? (by >> 4) : 0;
  const bf16_t* Ab = A + (long)by * 256 * 2048;
  const bf16_t* Bb = Wt + (long)which * 4194304 + (long)bx * 128 * 2048;
  const float* bias = TRIPLE ? (which == 0 ? b0 : (which == 1 ? b1 : b2)) : b0;

  const int lr = lane & 15;
  const int l8 = (lane >> 4) * 8;
  const f32x4 fv = {FILLV, FILLV, FILLV, FILLV};
  const int nblk = gridDim.x;

  f32x4 acc[8][2];
#pragma unroll
  for (int i = 0; i < 8; ++i)
#pragma unroll
    for (int j = 0; j < 2; ++j) acc[i][j] = (f32x4){0.f, 0.f, 0.f, 0.f};

  // prologue: stage tile 0 into buffer 0 (A0, A1, B = 6 loads/thread)
  stage_half(Ab, 0, smem, t);
  stage_half(Ab, 1, smem, t);
  stage_half(Bb, 0, smem + 32768, t);

  bf16x8 aF[4][2], bF[2][2];

  for (int kt = 0; kt < 32; ++kt) {
    const int cur = kt & 1;
    unsigned char* curA = smem + cur * 49152;
    unsigned char* curB = curA + 32768;
    unsigned char* nxtA = smem + (cur ^ 1) * 49152;
    unsigned char* nxtB = nxtA + 32768;
    const bool hn = kt < 31;
    const bf16_t* An = Ab + (kt + 1) * 64;
    const bf16_t* Bn = Bb + (kt + 1) * 64;
    const int arow = wr * 128 + lr;
    const int brow = wc * 32 + lr;
    f32x4* fillp = (f32x4*)attn + fillBase + ((long)kt * nblk + bid) * 1024 + t;

    // ---- phase 0: stage A-u0(next); VMCNT2 retires ALL prior-tile vmem
    if (hn) { stage_half(An, 0, nxtA, t); VMCNT2(); }
    else    { VMCNT0(); }
    BAR();
#pragma unroll
    for (int mi = 0; mi < 4; ++mi)
#pragma unroll
      for (int kk = 0; kk < 2; ++kk)
        aF[mi][kk] = lds_frag(curA, arow + mi * 16, kk * 32 + l8);
#pragma unroll
    for (int kk = 0; kk < 2; ++kk)
      bF[0][kk] = lds_frag(curB, brow, kk * 32 + l8);
    LGKM0(); SCHED0();
    __builtin_amdgcn_s_setprio(1);
#pragma unroll
    for (int mi = 0; mi < 4; ++mi)
#pragma unroll
      for (int kk = 0; kk < 2; ++kk)
        acc[mi][0] = __builtin_amdgcn_mfma_f32_16x16x32_bf16(
            aF[mi][kk], bF[0][kk], acc[mi][0], 0, 0, 0);
    __builtin_amdgcn_s_setprio(0);
    BAR();

    // ---- phase 1: stage A-u1(next) + fill; read bHi; mfma (rLo, cHi)
    if (hn) stage_half(An, 1, nxtA, t);
    __builtin_nontemporal_store(fv, fillp);
#pragma unroll
    for (int kk = 0; kk < 2; ++kk)
      bF[1][kk] = lds_frag(curB, brow + 16, kk * 32 + l8);
    BAR(); LGKM0(); SCHED0();
    __builtin_amdgcn_s_setprio(1);
#pragma unroll
    for (int mi = 0; mi < 4; ++mi)
#pragma unroll
      for (int kk = 0; kk < 2; ++kk)
        acc[mi][1] = __builtin_amdgcn_mfma_f32_16x16x32_bf16(
            aF[mi][kk], bF[1][kk], acc[mi][1], 0, 0, 0);
    __builtin_amdgcn_s_setprio(0);
    BAR();

    // ---- phase 2: stage B(next) + fill; read aHi; mfma (rHi, cLo)
    if (hn) stage_half(Bn, 0, nxtB, t);
    __builtin_nontemporal_store(fv, fillp + 512);
#pragma unroll
    for (int mi = 0; mi < 4; ++mi)
#pragma unroll
      for (int kk = 0; kk < 2; ++kk)
        aF[mi][kk] = lds_frag(curA, arow + 64 + mi * 16, kk * 32 + l8);
    BAR(); LGKM0(); SCHED0();
    __builtin_amdgcn_s_setprio(1);
#pragma unroll
    for (int mi = 0; mi < 4; ++mi)
#pragma unroll
      for (int kk = 0; kk < 2; ++kk)
        acc[4 + mi][0] = __builtin_amdgcn_mfma_f32_16x16x32_bf16(
            aF[mi][kk], bF[0][kk], acc[4 + mi][0], 0, 0, 0);
    __builtin_amdgcn_s_setprio(0);
    BAR();

    // ---- phase 3: mfma (rHi, cHi)
    BAR(); SCHED0();
    __builtin_amdgcn_s_setprio(1);
#pragma unroll
    for (int mi = 0; mi < 4; ++mi)
#pragma unroll
      for (int kk = 0; kk < 2; ++kk)
        acc[4 + mi][1] = __builtin_amdgcn_mfma_f32_16x16x32_bf16(
            aF[mi][kk], bF[1][kk], acc[4 + mi][1], 0, 0, 0);
    __builtin_amdgcn_s_setprio(0);
    BAR();
  }

  // Epilogue: per-wave LDS bounce -> vectorized C stores (R14).
  const int row0g = by * 256 + wr * 128;
  const int col0g = bx * 128 + wc * 32;
  float* lw = (float*)smem + wid * 2304;
#pragma unroll
  for (int p = 0; p < 2; ++p) {
    LGKM0();
#pragma unroll
    for (int mi = 0; mi < 4; ++mi)
#pragma unroll
      for (int ni = 0; ni < 2; ++ni) {
        const float bvv = bias[col0g + ni * 16 + lr];
#pragma unroll
        for (int j = 0; j < 4; ++j) {
          const int rl = mi * 16 + (lane >> 4) * 4 + j;
          lw[rl * 36 + ni * 16 + lr] = acc[p * 4 + mi][ni][j] + bvv;
        }
      }
    LGKM0(); SCHED0();
#pragma unroll
    for (int i = 0; i < 8; ++i) {
      const int c = i * 64 + lane;
      const int rl = c >> 3, cc = (c & 7) * 4;
      f32x4 v4 = *(const f32x4*)&lw[rl * 36 + cc];
      const long gaddr = (long)(row0g + p * 64 + rl) * 2048 + col0g + cc;
      if (OUTF32) {
        *(f32x4*)&((float*)C)[gaddr] = v4;
      } else {
        bf16x4 o = {(bf16_t)v4[0], (bf16_t)v4[1],
                    (bf16_t)v4[2], (bf16_t)v4[3]};
        *(bf16x4*)&((bf16_t*)C)[gaddr] = o;
      }
    }
  }
}

// ---------------------------------------------------------------------------
// m97-style bf16 GEMM (ctx only): C = A @ Bt^T, batched over grid.z.
// ---------------------------------------------------------------------------
__global__ __launch_bounds__(256) void gemm_bt(
    const bf16_t* __restrict__ A, const bf16_t* __restrict__ Bt,
    bf16_t* __restrict__ C, int K, int lda, int ldb, int ldc,
    long aBatchB, long aBatchH, long bBatchB, long bBatchH,
    long cBatchB, long cBatchH, int HperB)
{
  __shared__ bf16_t As[128 * 64];
  __shared__ bf16_t Bs[128 * 64];

  const int z  = blockIdx.z;
  const int zb = z / HperB, zh = z % HperB;
  const bf16_t* Ab = A  + (long)zb * aBatchB + (long)zh * aBatchH
                        + (long)blockIdx.y * 128 * lda;
  const bf16_t* Bb = Bt + (long)zb * bBatchB + (long)zh * bBatchH
                        + (long)blockIdx.x * 128 * ldb;

  const int t = threadIdx.x;
  const int lane = t & 63, w = t >> 6;
  const int wm = (w >> 1) * 64, wn = (w & 1) * 64;

  f32x4 acc[4][4];
#pragma unroll
  for (int i = 0; i < 4; ++i)
#pragma unroll
    for (int j = 0; j < 4; ++j) acc[i][j] = (f32x4){0.f, 0.f, 0.f, 0.f};

  for (int k0 = 0; k0 < K; k0 += 64) {
#pragma unroll
    for (int i = 0; i < 4; ++i) {
      int c = i * 256 + t;
      int row = c >> 3, col = (c & 7) * 8;
      gload16(Ab + (long)row * lda + k0 + col, &As[c * 8]);
      gload16(Bb + (long)row * ldb + k0 + col, &Bs[c * 8]);
    }
    __syncthreads();
#pragma unroll
    for (int kk = 0; kk < 2; ++kk) {
      bf16x8 af[4], bfr[4];
#pragma unroll
      for (int mi = 0; mi < 4; ++mi)
        af[mi] = *(const bf16x8*)&As[(wm + mi * 16 + (lane & 15)) * 64
                                     + kk * 32 + (lane >> 4) * 8];
#pragma unroll
      for (int ni = 0; ni < 4; ++ni)
        bfr[ni] = *(const bf16x8*)&Bs[(wn + ni * 16 + (lane & 15)) * 64
                                      + kk * 32 + (lane >> 4) * 8];
#pragma unroll
      for (int mi = 0; mi < 4; ++mi)
#pragma unroll
        for (int ni = 0; ni < 4; ++ni)
          acc[mi][ni] = __builtin_amdgcn_mfma_f32_16x16x32_bf16(
              af[mi], bfr[ni], acc[mi][ni], 0, 0, 0);
    }
    __syncthreads();
  }

  const long cb = (long)zb * cBatchB + (long)zh * cBatchH;
  const int row0 = blockIdx.y * 128 + wm;
  const int col0 = blockIdx.x * 128 + wn;
#pragma unroll
  for (int mi = 0; mi < 4; ++mi) {
#pragma unroll
    for (int ni = 0; ni < 4; ++ni) {
      const int col = col0 + ni * 16 + (lane & 15);
#pragma unroll
      for (int j = 0; j < 4; ++j) {
        const int row = row0 + mi * 16 + (lane >> 4) * 4 + j;
        C[cb + (long)row * ldc + col] = (bf16_t)acc[mi][ni][j];
      }
    }
  }
}

// ---------------------------------------------------------------------------
// Fused per-head feature map: Out = relu(A @ Wf1 + b1) @ Wf2 + b2.
// A staged via LDS (R13); weights read FRAGMENT-LINEAR (R15).
// ---------------------------------------------------------------------------
__global__ __launch_bounds__(256) void fm_fused(
    const bf16_t* __restrict__ A, const bf16_t* __restrict__ W1f,
    const bf16_t* __restrict__ W2f, const float* __restrict__ b1,
    const float* __restrict__ b2, bf16_t* __restrict__ Out)
{
  __shared__ __align__(16) unsigned char As_[16384];  // 64 rows x 256B, swz
  __shared__ char Hs[64 * 256 * 2];                   // 32 KB
  const int t = threadIdx.x, lane = t & 63, w = t >> 6;
  const long r0 = (long)blockIdx.x * 64;
  const int lr = lane & 15, lk = lane >> 4;

  // stage A-tile: 1024 chunks of 16B, 4/thread; inverse-swizzled source
  {
    const bf16_t* Ab = A + r0 * 128;
#pragma unroll
    for (int i = 0; i < 4; ++i) {
      int c = i * 256 + t;          // 0..1023
      int r = c >> 4;               // row 0..63 (16 chunks of 16B per row)
      int cc = ((c & 15) ^ (r & 7)) * 8;   // elems; XOR within 128B halves
      gload16(Ab + (long)r * 128 + cc, As_ + c * 16);
    }
  }
  __syncthreads();

  // phase A: H[64][256] = relu(A @ W1t^T + b1)
  f32x4 acc[4][4];
#pragma unroll
  for (int i = 0; i < 4; ++i)
#pragma unroll
    for (int j = 0; j < 4; ++j) acc[i][j] = (f32x4){0.f, 0.f, 0.f, 0.f};
  const int wn = w * 64;
#pragma unroll
  for (int kk = 0; kk < 4; ++kk) {
    bf16x8 af[4], bfr[4];
#pragma unroll
    for (int mi = 0; mi < 4; ++mi) {
      const int m = mi * 16 + lr;
      int byte = (m << 8) + kk * 64 + lk * 16;
      byte ^= (m & 7) << 4;
      af[mi] = *(const bf16x8*)(As_ + byte);
    }
#pragma unroll
    for (int ni = 0; ni < 4; ++ni)
      bfr[ni] = *(const bf16x8*)&W1f[((((w << 2) + ni) << 2) + kk) * 512
                                     + lane * 8];
#pragma unroll
    for (int mi = 0; mi < 4; ++mi)
#pragma unroll
      for (int ni = 0; ni < 4; ++ni)
        acc[mi][ni] = __builtin_amdgcn_mfma_f32_16x16x32_bf16(
            af[mi], bfr[ni], acc[mi][ni], 0, 0, 0);
  }
#pragma unroll
  for (int ni = 0; ni < 4; ++ni) {
    const int col = wn + ni * 16 + lr;
    const float bvv = b1[col];
#pragma unroll
    for (int mi = 0; mi < 4; ++mi)
#pragma unroll
      for (int j = 0; j < 4; ++j) {
        const int row = mi * 16 + lk * 4 + j;
        float h = fmaxf(acc[mi][ni][j] + bvv, 0.f);
        int byte = (row << 9) + (col << 1);
        byte ^= (row & 7) << 4;
        *(bf16_t*)(Hs + byte) = (bf16_t)h;
      }
  }
  __syncthreads();

  // phase B: C[64][128] = H @ W2t^T + b2
  f32x4 acc2[4][2];
#pragma unroll
  for (int i = 0; i < 4; ++i)
#pragma unroll
    for (int j = 0; j < 2; ++j) acc2[i][j] = (f32x4){0.f, 0.f, 0.f, 0.f};
  const int wn2 = w * 32;
#pragma unroll
  for (int kk = 0; kk < 8; ++kk) {
    bf16x8 af[4], bfr[2];
#pragma unroll
    for (int mi = 0; mi < 4; ++mi) {
      const int m = mi * 16 + lr;
      int byte = (m << 9) + kk * 64 + lk * 16;
      byte ^= (m & 7) << 4;
      af[mi] = *(const bf16x8*)(Hs + byte);
    }
#pragma unroll
    for (int ni = 0; ni < 2; ++ni)
      bfr[ni] = *(const bf16x8*)&W2f[((((w << 1) + ni) << 3) + kk) * 512
                                     + lane * 8];
#pragma unroll
    for (int mi = 0; mi < 4; ++mi)
#pragma unroll
      for (int ni = 0; ni < 2; ++ni)
        acc2[mi][ni] = __builtin_amdgcn_mfma_f32_16x16x32_bf16(
            af[mi], bfr[ni], acc2[mi][ni], 0, 0, 0);
  }
#pragma unroll
  for (int ni = 0; ni < 2; ++ni) {
    const int col = wn2 + ni * 16 + lr;
    const float bvv = b2[col];
#pragma unroll
    for (int mi = 0; mi < 4; ++mi)
#pragma unroll
      for (int j = 0; j < 4; ++j) {
        const int row = mi * 16 + lk * 4 + j;
        Out[(r0 + row) * 128 + col] = (bf16_t)(acc2[mi][ni][j] + bvv);
      }
  }
}

// ---------------------------------------------------------------------------
// prep v3: cvt (bf16x8 stores) + 64x64 big-W transposes (R14) + fm weights
// emitted FRAGMENT-LINEAR (blocks 16384/16385).
// ---------------------------------------------------------------------------
__global__ __launch_bounds__(256) void prep(
    const float* __restrict__ q, const float* __restrict__ k,
    const float* __restrict__ v,
    const float* __restrict__ Wq, const float* __restrict__ Wk,
    const float* __restrict__ Wv, const float* __restrict__ Wo,
    const float* __restrict__ Wf1, const float* __restrict__ Wf2,
    bf16_t* __restrict__ qkv_bf, bf16_t* __restrict__ Wqkv_t,
    bf16_t* __restrict__ Wf1_f, bf16_t* __restrict__ Wf2_f)
{
  const int t = threadIdx.x;
  const int bid = blockIdx.x;
  __shared__ float ts[64 * 65];

  if (bid < 12288) {
    const float* in = bid < 4096 ? q : (bid < 8192 ? k : v);
    bf16_t* o = qkv_bf + (long)(bid >> 12) * 8388608L;
    const long base = (long)(bid & 4095) * 2048 + t * 8;
    float4 x0 = *(const float4*)&in[base];
    float4 x1 = *(const float4*)&in[base + 4];
    bf16x8 r = {(bf16_t)x0.x, (bf16_t)x0.y, (bf16_t)x0.z, (bf16_t)x0.w,
                (bf16_t)x1.x, (bf16_t)x1.y, (bf16_t)x1.z, (bf16_t)x1.w};
    *(bf16x8*)&o[base] = r;
    return;
  }

  if (bid >= 16384) {
    // fm weights in fragment-linear layout (4096 frags of 8 elems each)
    const bool isW2 = (bid == 16385);
    const float* Wsrc = isW2 ? Wf2 : Wf1;
    bf16_t* dst = isW2 ? Wf2_f : Wf1_f;
    const int Nd2 = isW2 ? 128 : 256;
#pragma unroll
    for (int i = 0; i < 16; ++i) {
      const int idx = t * 16 + i;       // 0..4095
      const int ln = idx & 63;
      int kk, col;
      if (!isW2) {
        kk = (idx >> 6) & 3;
        const int ni = (idx >> 8) & 3, ww = idx >> 10;
        col = ww * 64 + ni * 16 + (ln & 15);
      } else {
        kk = (idx >> 6) & 7;
        const int ni = (idx >> 9) & 1, ww = idx >> 10;
        col = ww * 32 + ni * 16 + (ln & 15);
      }
      const int krow = kk * 32 + (ln >> 4) * 8;
      bf16x8 vv;
#pragma unroll
      for (int e = 0; e < 8; ++e)
        vv[e] = (bf16_t)Wsrc[(long)(krow + e) * Nd2 + col];
      *(bf16x8*)&dst[(long)idx * 8] = vv;
    }
    return;
  }

  // big 2048x2048 weight transposes, 64x64 tiles (R14)
  const int tile = bid - 12288;
  const int wsel = tile >> 10, r = tile & 1023;
  const float* W = wsel == 0 ? Wq : wsel == 1 ? Wk : wsel == 2 ? Wv : Wo;
  bf16_t* outp = Wqkv_t + (long)wsel * 4194304L;
  const int k0 = (r >> 5) * 64, n0 = (r & 31) * 64;

#pragma unroll
  for (int i = 0; i < 4; ++i) {
    const int idx = i * 256 + t;
    const int rr = idx >> 4, cc = (idx & 15) * 4;
    float4 x = *(const float4*)&W[(long)(k0 + rr) * 2048 + n0 + cc];
    float* p = &ts[rr * 65 + cc];
    p[0] = x.x; p[1] = x.y; p[2] = x.z; p[3] = x.w;
  }
  __syncthreads();

#pragma unroll
  for (int i = 0; i < 2; ++i) {
    const int idx = i * 256 + t;
    const int n = idx >> 3, kc = (idx & 7) * 8;
    bf16x8 vv;
#pragma unroll
    for (int qq = 0; qq < 8; ++qq) vv[qq] = (bf16_t)ts[(kc + qq) * 65 + n];
    *(bf16x8*)&outp[(long)(n0 + n) * 2048 + k0 + kc] = vv;
  }
}

// ---------------------------------------------------------------------------
// Partial KV^T + per-chunk K-sums. Split 8: grid (8, 32), 256 s-rows/block.
// ---------------------------------------------------------------------------
__global__ __launch_bounds__(256) void kv_partial(
    const bf16_t* __restrict__ Kf, const bf16_t* __restrict__ Vp,
    float* __restrict__ part, float* __restrict__ part_denom) {
  const int z = blockIdx.y, b = z >> 4, h = z & 15;
  const int s0 = blockIdx.x * 256;
  const int t = threadIdx.x;
  __shared__ bf16_t Ks[32 * 128];
  __shared__ bf16_t Vs[32 * 128];
  __shared__ float red[4];
  const bf16_t* Kb = Kf + (long)b * 4194304 + h * 128;
  const bf16_t* Vb = Vp + (long)b * 4194304 + h * 128;
  float acc[8][8];
#pragma unroll
  for (int i = 0; i < 8; ++i)
#pragma unroll
    for (int j = 0; j < 8; ++j) acc[i][j] = 0.f;
  float ksum = 0.f;
  const int d0 = (t & 15) * 8, e0 = (t >> 4) * 8;
  for (int sc = 0; sc < 256; sc += 32) {
#pragma unroll
    for (int i = 0; i < 2; ++i) {
      int idx = (i * 256 + t) * 8;
      int r = idx >> 7, c = idx & 127;
      long g = (long)(s0 + sc + r) * 2048 + c;
      *(bf16x8*)&Ks[r * 128 + c] = *(const bf16x8*)&Kb[g];
      *(bf16x8*)&Vs[r * 128 + c] = *(const bf16x8*)&Vb[g];
    }
    __syncthreads();
    {
      bf16x8 a0 = *(const bf16x8*)&Ks[t * 16];
      bf16x8 a1 = *(const bf16x8*)&Ks[t * 16 + 8];
#pragma unroll
      for (int j = 0; j < 8; ++j) ksum += (float)a0[j] + (float)a1[j];
    }
    for (int s = 0; s < 32; ++s) {
      bf16x8 kv = *(const bf16x8*)&Ks[s * 128 + d0];
      bf16x8 vv = *(const bf16x8*)&Vs[s * 128 + e0];
      float kf[8], vf[8];
#pragma unroll
      for (int i = 0; i < 8; ++i) { kf[i] = (float)kv[i]; vf[i] = (float)vv[i]; }
#pragma unroll
      for (int i = 0; i < 8; ++i)
#pragma unroll
        for (int j = 0; j < 8; ++j) acc[i][j] += vf[i] * kf[j];
    }
    __syncthreads();
  }

#pragma unroll
  for (int off = 32; off; off >>= 1) ksum += __shfl_down(ksum, off, 64);
  if ((t & 63) == 0) red[t >> 6] = ksum;
  __syncthreads();
  if (t == 0)
    part_denom[blockIdx.x * 32 + z] = red[0] + red[1] + red[2] + red[3];

  float* pb = part + ((long)blockIdx.x * 32 + z) * 16384;
#pragma unroll
  for (int i = 0; i < 8; ++i)
#pragma unroll
    for (int j = 0; j < 8; ++j)
      pb[(e0 + i) * 128 + (d0 + j)] = acc[i][j];
}

// ---------------------------------------------------------------------------
// kv_reduce: 512 blocks; z = bid>>4, slice = bid&15; one float4/thread.
// ---------------------------------------------------------------------------
__global__ __launch_bounds__(256) void kv_reduce(
    const float* __restrict__ part, const float* __restrict__ part_denom,
    bf16_t* __restrict__ KVT) {
  const int z = blockIdx.x >> 4, slice = blockIdx.x & 15;
  const int t = threadIdx.x;
  float dsum = 0.f;
#pragma unroll
  for (int c = 0; c < 8; ++c) dsum += part_denom[c * 32 + z];
  const float inv = 1.0f / (dsum + 1e-8f);
  const long i0 = slice * 1024 + t * 4;
  f32x4 s = {0.f, 0.f, 0.f, 0.f};
#pragma unroll
  for (int c = 0; c < 8; ++c) {
    f32x4 v = *(const f32x4*)&part[((long)c * 32 + z) * 16384 + i0];
    s.x += v.x; s.y += v.y; s.z += v.z; s.w += v.w;
  }
  bf16x4 o = {(bf16_t)(s.x * inv), (bf16_t)(s.y * inv),
              (bf16_t)(s.z * inv), (bf16_t)(s.w * inv)};
  *(bf16x4*)&KVT[(long)z * 16384 + i0] = o;
}

// ---------------------------------------------------------------------------
extern "C" void kernel_launch(void* const* d_in, const int* in_sizes, int n_in,
                              void* d_out, int out_size, void* d_ws, size_t ws_size,
                              hipStream_t stream) {
  (void)in_sizes; (void)n_in; (void)out_size; (void)ws_size;
  const float* q   = (const float*)d_in[0];
  const float* k   = (const float*)d_in[1];
  const float* v   = (const float*)d_in[2];
  const float* Wq  = (const float*)d_in[3];
  const float* bq  = (const float*)d_in[4];
  const float* Wk  = (const float*)d_in[5];
  const float* bk  = (const float*)d_in[6];
  const float* Wv  = (const float*)d_in[7];
  const float* bv  = (const float*)d_in[8];
  const float* Wo  = (const float*)d_in[9];
  const float* bo  = (const float*)d_in[10];
  const float* Wf1 = (const float*)d_in[11];
  const float* bf1 = (const float*)d_in[12];
  const float* Wf2 = (const float*)d_in[13];
  const float* bf2 = (const float*)d_in[14];

  bf16_t* P      = (bf16_t*)d_ws;
  bf16_t* qkv_bf = P;                  // [3][4096][2048]
  bf16_t* Wqkv_t = P + 25165824L;      // [4][2048][2048]
  bf16_t* Wo_t   = P + 37748736L;
  bf16_t* Qp     = P + 42008576L;      // [12288][2048] stacked Qp,Kp,Vp
  bf16_t* Vp     = P + 58785792L;      // later reused as context
  bf16_t* Qf     = P + 83951616L;      // [131072][128] stacked Qf,Kf
  bf16_t* Kf     = P + 92340224L;
  bf16_t* KVT    = P + 100728832L;     // [32][128][128]
  bf16_t* Wf1_f  = P + 101253120L;     // [4096][8] fragment-linear
  bf16_t* Wf2_f  = P + 101285888L;     // [4096][8]
  float*  part   = (float*)d_ws;       // [8][32][128][128] f32 over dead qkv_bf
  float*  part_denom = (float*)d_ws + 4194304L;   // [8][32]

  float* out0 = (float*)d_out;                 // [2,2048,2048]
  float* attn = (float*)d_out + 8388608L;      // [2,16,2048,2048]

  dim3 blk(256);

  // 1. prep v3: cvt q/k/v + weight transposes + fragment-linear fm weights
  prep<<<16386, blk, 0, stream>>>(q, k, v, Wq, Wk, Wv, Wo, Wf1, Wf2,
                                  qkv_bf, Wqkv_t, Wf1_f, Wf2_f);

  // 2. 8-phase fused Q/K/V projection, 768 blocks (+ fill [0, 25165824))
  gemm8<false, true><<<768, 512, 0, stream>>>(
      qkv_bf, Wqkv_t, bq, bk, bv, Qp, attn, 0L);

  // 3. fused feature map over Qp||Kp -> Qf||Kf (frag-linear weights)
  fm_fused<<<2048, blk, 0, stream>>>(Qp, Wf1_f, Wf2_f, bf1, bf2, Qf);

  // 4. KV^T partials + K-sums (split 8)
  kv_partial<<<dim3(8, 32), blk, 0, stream>>>(Kf, Vp, part, part_denom);

  // 5. reduce partials (+denom)
  kv_reduce<<<512, blk, 0, stream>>>(part, part_denom, KVT);

  // 6. context = Qf @ KVT^T batched over 32 (b,h)
  gemm_bt<<<dim3(1, 16, 32), blk, 0, stream>>>(
      Qf, KVT, Vp, 128, 2048, 128, 2048,
      4194304L, 128L, 262144L, 16384L, 4194304L, 128L, 16);

  // 7. output = context @ Wo + bo, 8-phase 256 blocks
  //    (+ fill [25165824, 33554432))
  gemm8<true, false><<<256, 512, 0, stream>>>(
      Vp, Wo_t, bo, nullptr, nullptr, out0, attn, 25165824L);
}